// Round 5
// baseline (2622.200 us; speedup 1.0000x reference)
//
#include <hip/hip_runtime.h>
#include <hip/hip_bf16.h>

#define NNODES 100000
#define NEDGES 1600000
#define IN_F 16
#define HID 128
#define NLAYERS 8
#define BN_EPS 1e-5f
#define BLOBSZ 532480   // ushorts per blob half: 8192 + 16*32768

typedef __attribute__((ext_vector_type(8))) short short8;
typedef __attribute__((ext_vector_type(4))) float f32x4;
typedef __attribute__((ext_vector_type(4))) unsigned int uint32x4;
typedef unsigned short ushort_t;
typedef unsigned int uint_t;

__device__ __forceinline__ ushort_t f2bf(float f) {
  uint_t u = __builtin_bit_cast(uint_t, f);
  uint_t r = (u + 0x7fffu + ((u >> 16) & 1u)) >> 16;
  return (ushort_t)r;
}
__device__ __forceinline__ float bfl(uint_t u) {
  return __builtin_bit_cast(float, u << 16);
}
// RNE split for weights (preconv, off critical path)
__device__ __forceinline__ void bsplit(float v, ushort_t& h, ushort_t& l) {
  h = f2bf(v);
  float r = v - bfl((uint_t)h);
  l = f2bf(r);
}

// cheap truncation split of 8 fp32 -> hi/lo short8 (err <= 2^-16 rel)
__device__ __forceinline__ void split8(const float* v, short8& h8, short8& l8) {
  uint_t hp[4], lp[4];
#pragma unroll
  for (int j = 0; j < 4; ++j) {
    float v0 = v[2 * j], v1 = v[2 * j + 1];
    uint_t u0 = __builtin_bit_cast(uint_t, v0);
    uint_t u1 = __builtin_bit_cast(uint_t, v1);
    uint_t h0 = u0 & 0xFFFF0000u;
    uint_t h1 = u1 & 0xFFFF0000u;
    float r0 = v0 - __builtin_bit_cast(float, h0);
    float r1 = v1 - __builtin_bit_cast(float, h1);
    hp[j] = (h0 >> 16) | h1;
    lp[j] = (__builtin_bit_cast(uint_t, r0) >> 16) |
            (__builtin_bit_cast(uint_t, r1) & 0xFFFF0000u);
  }
  h8 = __builtin_bit_cast(short8, (uint32x4){hp[0], hp[1], hp[2], hp[3]});
  l8 = __builtin_bit_cast(short8, (uint32x4){lp[0], lp[1], lp[2], lp[3]});
}

// ============================ CSR build ============================

__global__ void hist_kernel(const int* __restrict__ dst, int* __restrict__ deg, int E) {
  int i = blockIdx.x * blockDim.x + threadIdx.x;
  if (i < E) atomicAdd(&deg[dst[i]], 1);
}

__global__ void scan1_kernel(const int* __restrict__ deg, int* __restrict__ bsum, int N) {
  __shared__ int sdata[256];
  int b = blockIdx.x, t = threadIdx.x;
  int base = b * 1024 + t * 4;
  int s = 0;
#pragma unroll
  for (int j = 0; j < 4; ++j) {
    int i = base + j;
    if (i < N) s += deg[i];
  }
  sdata[t] = s;
  __syncthreads();
  for (int off = 128; off > 0; off >>= 1) {
    if (t < off) sdata[t] += sdata[t + off];
    __syncthreads();
  }
  if (t == 0) bsum[b] = sdata[0];
}

__global__ void scan2_kernel(const int* __restrict__ bsum, int* __restrict__ boff,
                             int nb, int* __restrict__ row_ptr, int N, int E) {
  __shared__ int s[256];
  int t = threadIdx.x;
  s[t] = (t < nb) ? bsum[t] : 0;
  __syncthreads();
  for (int off = 1; off < 256; off <<= 1) {
    int v = (t >= off) ? s[t - off] : 0;
    __syncthreads();
    s[t] += v;
    __syncthreads();
  }
  boff[t] = (t == 0) ? 0 : s[t - 1];
  if (t == 0) row_ptr[N] = E;
}

__global__ void scan3_kernel(const int* __restrict__ deg, const int* __restrict__ boff,
                             int* __restrict__ row_ptr, int* __restrict__ cursor, int N) {
  __shared__ int sdata[256];
  int b = blockIdx.x, t = threadIdx.x;
  int base = b * 1024 + t * 4;
  int v[4];
  int s = 0;
#pragma unroll
  for (int j = 0; j < 4; ++j) {
    int i = base + j;
    v[j] = (i < N) ? deg[i] : 0;
    s += v[j];
  }
  sdata[t] = s;
  __syncthreads();
  for (int off = 1; off < 256; off <<= 1) {
    int u = (t >= off) ? sdata[t - off] : 0;
    __syncthreads();
    sdata[t] += u;
    __syncthreads();
  }
  int excl = boff[b] + ((t == 0) ? 0 : sdata[t - 1]);
#pragma unroll
  for (int j = 0; j < 4; ++j) {
    int i = base + j;
    if (i < N) {
      row_ptr[i] = excl;
      cursor[i] = excl;
      excl += v[j];
    }
  }
}

__global__ void fill_kernel(const int* __restrict__ src, const int* __restrict__ dst,
                            int* __restrict__ cursor, int* __restrict__ colb, int E) {
  int i = blockIdx.x * blockDim.x + threadIdx.x;
  if (i < E) {
    int d = dst[i];
    int pos = atomicAdd(&cursor[d], 1);
    colb[pos] = src[i];
  }
}

// =================== weight pre-convert: split hi/lo MFMA-frag blobs ===================
__global__ void preconv_kernel(const float* __restrict__ W1_0, const float* __restrict__ W1,
                               const float* __restrict__ W2, const float* __restrict__ Wr1,
                               ushort_t* __restrict__ WB) {
  int g = blockIdx.y;
  int e = blockIdx.x * 256 + threadIdx.x;
  int KP = (g == 0) ? 32 : 128;
  if (e >= KP * 128) return;
  int k = e >> 7, n = e & 127;
  float v;
  if (g == 0) v = (k < 16) ? W1_0[k * 128 + n] : 0.0f;
  else if (g <= 7) v = W1[(size_t)(g - 1) * 16384 + e];
  else if (g <= 15) v = W2[(size_t)(g - 8) * 16384 + e];
  else v = Wr1[e];
  size_t base = (g == 0) ? 0 : (8192 + (size_t)(g - 1) * 32768);
  int unit = ((k >> 5) << 9) + ((n >> 4) << 6) + (n & 15) + (((k >> 3) & 3) << 4);
  ushort_t h, l;
  bsplit(v, h, l);
  WB[base + (size_t)unit * 8 + (k & 7)] = h;
  WB[BLOBSZ + base + (size_t)unit * 8 + (k & 7)] = l;
}

// ============================ Aggregation ============================

__global__ __launch_bounds__(256) void agg16_kernel(
    const float* __restrict__ X, const int* __restrict__ rp, const int* __restrict__ colb,
    const float* __restrict__ eps, float* __restrict__ Z, int N) {
  int g = threadIdx.x >> 3;
  int l = threadIdx.x & 7;
  int n = blockIdx.x * 32 + g;
  if (n >= N) return;
  float e = 1.0f + eps[0];
  const float2* X2 = (const float2*)X;
  float2 self = X2[(size_t)n * 8 + l];
  float2 acc = make_float2(self.x * e, self.y * e);
  float2 acc2 = make_float2(0.0f, 0.0f);
  int beg = rp[n], end = rp[n + 1];
  int p = beg;
  for (; p + 4 <= end; p += 4) {
    int s0 = colb[p], s1 = colb[p + 1], s2 = colb[p + 2], s3 = colb[p + 3];
    float2 v0 = X2[(size_t)s0 * 8 + l];
    float2 v1 = X2[(size_t)s1 * 8 + l];
    float2 v2 = X2[(size_t)s2 * 8 + l];
    float2 v3 = X2[(size_t)s3 * 8 + l];
    acc.x += v0.x; acc.y += v0.y;
    acc2.x += v1.x; acc2.y += v1.y;
    acc.x += v2.x; acc.y += v2.y;
    acc2.x += v3.x; acc2.y += v3.y;
  }
  for (; p < end; ++p) {
    int s = colb[p];
    float2 v = X2[(size_t)s * 8 + l];
    acc.x += v.x; acc.y += v.y;
  }
  acc.x += acc2.x; acc.y += acc2.y;
  ((float2*)Z)[(size_t)n * 8 + l] = acc;
}

// layers 1..7: fp32 Y, fused h=relu(a*y+c), SKIP += h(self), Z fp32
__global__ __launch_bounds__(256) void agg128_kernel(
    const float* __restrict__ Y, const float* __restrict__ av, const float* __restrict__ cv,
    const int* __restrict__ rp, const int* __restrict__ colb,
    const float* __restrict__ eps, int layer, float* __restrict__ Z,
    float* __restrict__ SKIP, int N) {
  int wv = threadIdx.x >> 6;
  int lane = threadIdx.x & 63;
  int n = blockIdx.x * 4 + wv;
  if (n >= N) return;
  float e = 1.0f + eps[layer];
  float2 a2 = *(const float2*)(av + lane * 2);
  float2 c2 = *(const float2*)(cv + lane * 2);
  const float2* Y2 = (const float2*)Y;
  float2 sv = Y2[(size_t)n * 64 + lane];
  float hx = fmaxf(fmaf(a2.x, sv.x, c2.x), 0.0f);
  float hy = fmaxf(fmaf(a2.y, sv.y, c2.y), 0.0f);
  if (SKIP) {
    float2* S2 = (float2*)SKIP;
    float2 s = S2[(size_t)n * 64 + lane];
    s.x += hx; s.y += hy;
    S2[(size_t)n * 64 + lane] = s;
  }
  float ax = hx * e, ay = hy * e;
  float bx = 0.0f, by = 0.0f, cx = 0.0f, cy = 0.0f, dx = 0.0f, dy = 0.0f;
  int beg = rp[n], end = rp[n + 1];
  int p = beg;
  for (; p + 8 <= end; p += 8) {
    int s0 = colb[p], s1 = colb[p + 1], s2 = colb[p + 2], s3 = colb[p + 3];
    int s4 = colb[p + 4], s5 = colb[p + 5], s6 = colb[p + 6], s7 = colb[p + 7];
    float2 v0 = Y2[(size_t)s0 * 64 + lane];
    float2 v1 = Y2[(size_t)s1 * 64 + lane];
    float2 v2 = Y2[(size_t)s2 * 64 + lane];
    float2 v3 = Y2[(size_t)s3 * 64 + lane];
    float2 v4 = Y2[(size_t)s4 * 64 + lane];
    float2 v5 = Y2[(size_t)s5 * 64 + lane];
    float2 v6 = Y2[(size_t)s6 * 64 + lane];
    float2 v7 = Y2[(size_t)s7 * 64 + lane];
    ax += fmaxf(fmaf(a2.x, v0.x, c2.x), 0.0f);
    ay += fmaxf(fmaf(a2.y, v0.y, c2.y), 0.0f);
    bx += fmaxf(fmaf(a2.x, v1.x, c2.x), 0.0f);
    by += fmaxf(fmaf(a2.y, v1.y, c2.y), 0.0f);
    cx += fmaxf(fmaf(a2.x, v2.x, c2.x), 0.0f);
    cy += fmaxf(fmaf(a2.y, v2.y, c2.y), 0.0f);
    dx += fmaxf(fmaf(a2.x, v3.x, c2.x), 0.0f);
    dy += fmaxf(fmaf(a2.y, v3.y, c2.y), 0.0f);
    ax += fmaxf(fmaf(a2.x, v4.x, c2.x), 0.0f);
    ay += fmaxf(fmaf(a2.y, v4.y, c2.y), 0.0f);
    bx += fmaxf(fmaf(a2.x, v5.x, c2.x), 0.0f);
    by += fmaxf(fmaf(a2.y, v5.y, c2.y), 0.0f);
    cx += fmaxf(fmaf(a2.x, v6.x, c2.x), 0.0f);
    cy += fmaxf(fmaf(a2.y, v6.y, c2.y), 0.0f);
    dx += fmaxf(fmaf(a2.x, v7.x, c2.x), 0.0f);
    dy += fmaxf(fmaf(a2.y, v7.y, c2.y), 0.0f);
  }
  for (; p < end; ++p) {
    int s = colb[p];
    float2 v = Y2[(size_t)s * 64 + lane];
    ax += fmaxf(fmaf(a2.x, v.x, c2.x), 0.0f);
    ay += fmaxf(fmaf(a2.y, v.y, c2.y), 0.0f);
  }
  ax += bx + cx + dx;
  ay += by + cy + dy;
  ((float2*)Z)[(size_t)n * 64 + lane] = make_float2(ax, ay);
}

// ============================ LDS-free split-bf16 MFMA GEMM ============================
// C(fp32)[M,128] = op(A)[M,K] @ B + bias via A_hi*B_hi + A_lo*B_hi + A_hi*B_lo.
// A fragments loaded per-lane directly from global (8 consecutive fp32 = one frag);
// B fragments loaded per-lane from the frag-ordered blob (1 KB contiguous per wave).
// No LDS staging, no barriers in the K loop.
// MODE 0: op=A   MODE 1: op=relu(pa*A+pc)   MODE 2: op=0.25*(A + relu(pa*A2+pc))
// MODE 3: A fp32 [M,16], K=32 zero-padded (blob rows 16..31 pre-zeroed)
template <int KTOT, int MODE>
__global__ __launch_bounds__(256, 4) void gemm_mfma(
    const float* __restrict__ A, const float* __restrict__ A2f,
    const ushort_t* __restrict__ Bhi, const ushort_t* __restrict__ Blo,
    const float* __restrict__ bias,
    const float* __restrict__ pa, const float* __restrict__ pc,
    float* __restrict__ C,
    float* __restrict__ gsum, float* __restrict__ gsq,
    float* __restrict__ aout, float* __restrict__ cout, int* __restrict__ cnt,
    const float* __restrict__ gamma, const float* __restrict__ beta,
    float invN, int M, int nb) {
  __shared__ float s_sum[128];
  __shared__ float s_sq[128];
  __shared__ int s_last;
  const int tid = threadIdx.x;
  const int w = tid >> 6;
  const int lane = tid & 63;
  const int ln = lane & 15;
  const int quad = lane >> 4;
  const int brow = blockIdx.x * 128;
  constexpr int AST = (MODE == 3) ? 16 : KTOT;  // A row stride (fp32 elems)

  int r0 = brow + (w << 5) + ln;       if (r0 >= M) r0 = M - 1;
  int r1 = brow + (w << 5) + 16 + ln;  if (r1 >= M) r1 = M - 1;

  f32x4 acc[2][8];
#pragma unroll
  for (int rt = 0; rt < 2; ++rt)
#pragma unroll
    for (int ct = 0; ct < 8; ++ct) acc[rt][ct] = (f32x4){0.0f, 0.0f, 0.0f, 0.0f};

  constexpr int KC = KTOT / 32;
#pragma unroll
  for (int kcl = 0; kcl < KC; ++kcl) {
    const int kb = (kcl << 5) + (quad << 3);
    float e0[8], e1[8];
    if constexpr (MODE == 3) {
      if (kb < 16) {
        float4 a0 = *(const float4*)(A + (size_t)r0 * AST + kb);
        float4 a1 = *(const float4*)(A + (size_t)r0 * AST + kb + 4);
        e0[0] = a0.x; e0[1] = a0.y; e0[2] = a0.z; e0[3] = a0.w;
        e0[4] = a1.x; e0[5] = a1.y; e0[6] = a1.z; e0[7] = a1.w;
        float4 b0 = *(const float4*)(A + (size_t)r1 * AST + kb);
        float4 b1 = *(const float4*)(A + (size_t)r1 * AST + kb + 4);
        e1[0] = b0.x; e1[1] = b0.y; e1[2] = b0.z; e1[3] = b0.w;
        e1[4] = b1.x; e1[5] = b1.y; e1[6] = b1.z; e1[7] = b1.w;
      } else {
#pragma unroll
        for (int j = 0; j < 8; ++j) { e0[j] = 0.0f; e1[j] = 0.0f; }
      }
    } else {
      float4 a0 = *(const float4*)(A + (size_t)r0 * AST + kb);
      float4 a1 = *(const float4*)(A + (size_t)r0 * AST + kb + 4);
      float4 b0 = *(const float4*)(A + (size_t)r1 * AST + kb);
      float4 b1 = *(const float4*)(A + (size_t)r1 * AST + kb + 4);
      e0[0] = a0.x; e0[1] = a0.y; e0[2] = a0.z; e0[3] = a0.w;
      e0[4] = a1.x; e0[5] = a1.y; e0[6] = a1.z; e0[7] = a1.w;
      e1[0] = b0.x; e1[1] = b0.y; e1[2] = b0.z; e1[3] = b0.w;
      e1[4] = b1.x; e1[5] = b1.y; e1[6] = b1.z; e1[7] = b1.w;
      if constexpr (MODE == 1) {
        float4 p0 = *(const float4*)(pa + kb);
        float4 p1 = *(const float4*)(pa + kb + 4);
        float4 q0 = *(const float4*)(pc + kb);
        float4 q1 = *(const float4*)(pc + kb + 4);
        float pp[8] = {p0.x, p0.y, p0.z, p0.w, p1.x, p1.y, p1.z, p1.w};
        float qq[8] = {q0.x, q0.y, q0.z, q0.w, q1.x, q1.y, q1.z, q1.w};
#pragma unroll
        for (int j = 0; j < 8; ++j) {
          e0[j] = fmaxf(fmaf(pp[j], e0[j], qq[j]), 0.0f);
          e1[j] = fmaxf(fmaf(pp[j], e1[j], qq[j]), 0.0f);
        }
      } else if constexpr (MODE == 2) {
        float4 y00 = *(const float4*)(A2f + (size_t)r0 * AST + kb);
        float4 y01 = *(const float4*)(A2f + (size_t)r0 * AST + kb + 4);
        float4 y10 = *(const float4*)(A2f + (size_t)r1 * AST + kb);
        float4 y11 = *(const float4*)(A2f + (size_t)r1 * AST + kb + 4);
        float4 p0 = *(const float4*)(pa + kb);
        float4 p1 = *(const float4*)(pa + kb + 4);
        float4 q0 = *(const float4*)(pc + kb);
        float4 q1 = *(const float4*)(pc + kb + 4);
        float y0a[8] = {y00.x, y00.y, y00.z, y00.w, y01.x, y01.y, y01.z, y01.w};
        float y1a[8] = {y10.x, y10.y, y10.z, y10.w, y11.x, y11.y, y11.z, y11.w};
        float pp[8] = {p0.x, p0.y, p0.z, p0.w, p1.x, p1.y, p1.z, p1.w};
        float qq[8] = {q0.x, q0.y, q0.z, q0.w, q1.x, q1.y, q1.z, q1.w};
#pragma unroll
        for (int j = 0; j < 8; ++j) {
          e0[j] = 0.25f * (e0[j] + fmaxf(fmaf(pp[j], y0a[j], qq[j]), 0.0f));
          e1[j] = 0.25f * (e1[j] + fmaxf(fmaf(pp[j], y1a[j], qq[j]), 0.0f));
        }
      }
    }
    short8 a0h, a0l, a1h, a1l;
    split8(e0, a0h, a0l);
    split8(e1, a1h, a1l);
    const ushort_t* bh_base = Bhi + (((size_t)(kcl << 9) + lane) << 3);
    const ushort_t* bl_base = Blo + (((size_t)(kcl << 9) + lane) << 3);
#pragma unroll
    for (int ct = 0; ct < 8; ++ct) {
      short8 bh = *(const short8*)(bh_base + (ct << 9));
      short8 bl = *(const short8*)(bl_base + (ct << 9));
      acc[0][ct] = __builtin_amdgcn_mfma_f32_16x16x32_bf16(a0h, bh, acc[0][ct], 0, 0, 0);
      acc[0][ct] = __builtin_amdgcn_mfma_f32_16x16x32_bf16(a0l, bh, acc[0][ct], 0, 0, 0);
      acc[0][ct] = __builtin_amdgcn_mfma_f32_16x16x32_bf16(a0h, bl, acc[0][ct], 0, 0, 0);
      acc[1][ct] = __builtin_amdgcn_mfma_f32_16x16x32_bf16(a1h, bh, acc[1][ct], 0, 0, 0);
      acc[1][ct] = __builtin_amdgcn_mfma_f32_16x16x32_bf16(a1l, bh, acc[1][ct], 0, 0, 0);
      acc[1][ct] = __builtin_amdgcn_mfma_f32_16x16x32_bf16(a1h, bl, acc[1][ct], 0, 0, 0);
    }
  }

  // ---- epilogue: bias, stats, fp32 store ----
  if (tid < 128) { s_sum[tid] = 0.0f; s_sq[tid] = 0.0f; }
  __syncthreads();
#pragma unroll
  for (int ct = 0; ct < 8; ++ct) {
    int col = (ct << 4) + ln;
    float bsc = bias[col];
    float csum = 0.0f, csq = 0.0f;
#pragma unroll
    for (int rt = 0; rt < 2; ++rt) {
#pragma unroll
      for (int i = 0; i < 4; ++i) {
        int row = brow + (w << 5) + (rt << 4) + (quad << 2) + i;
        if (row < M) {
          float y = acc[rt][ct][i] + bsc;
          csum += y; csq += y * y;
          C[(size_t)row * 128 + col] = y;
        }
      }
    }
    atomicAdd(&s_sum[col], csum);
    atomicAdd(&s_sq[col], csq);
  }
  __syncthreads();
  if (tid < 128) {
    atomicAdd(&gsum[tid], s_sum[tid]);
    atomicAdd(&gsq[tid], s_sq[tid]);
  }
  if (tid == 0) {
    __threadfence();
    int v = __hip_atomic_fetch_add(cnt, 1, __ATOMIC_ACQ_REL, __HIP_MEMORY_SCOPE_AGENT);
    s_last = (v == nb - 1) ? 1 : 0;
  }
  __syncthreads();
  if (s_last && tid < 128) {
    float s = __hip_atomic_load(&gsum[tid], __ATOMIC_RELAXED, __HIP_MEMORY_SCOPE_AGENT);
    float q = __hip_atomic_load(&gsq[tid], __ATOMIC_RELAXED, __HIP_MEMORY_SCOPE_AGENT);
    float mu = s * invN;
    float var = q * invN - mu * mu;
    float sc = gamma[tid] * rsqrtf(var + BN_EPS);
    aout[tid] = sc;
    cout[tid] = beta[tid] - sc * mu;
  }
}

// ============================ regressor head ============================
__global__ __launch_bounds__(256) void finaldot_kernel(
    const float* __restrict__ Y, const float* __restrict__ a, const float* __restrict__ c,
    const float* __restrict__ Wr2, const float* __restrict__ br2,
    float* __restrict__ out, int N) {
  int wv = threadIdx.x >> 6;
  int lane = threadIdx.x & 63;
  int n = blockIdx.x * 4 + wv;
  if (n >= N) return;
  float2 y = *(const float2*)(Y + (size_t)n * HID + lane * 2);
  int c0 = lane * 2;
  float s = fmaxf(fmaf(a[c0], y.x, c[c0]), 0.0f) * Wr2[c0] +
            fmaxf(fmaf(a[c0 + 1], y.y, c[c0 + 1]), 0.0f) * Wr2[c0 + 1];
  for (int off = 32; off > 0; off >>= 1) s += __shfl_down(s, off, 64);
  if (lane == 0) out[n] = 1.0f / (1.0f + expf(-(s + br2[0])));
}

// ============================ launch ============================
extern "C" void kernel_launch(void* const* d_in, const int* in_sizes, int n_in,
                              void* d_out, int out_size, void* d_ws, size_t ws_size,
                              hipStream_t stream) {
  const float* x     = (const float*)d_in[0];
  const int*   ei    = (const int*)d_in[1];
  const float* eps   = (const float*)d_in[2];
  const float* W1_0  = (const float*)d_in[3];
  const float* b1_0  = (const float*)d_in[4];
  const float* W1    = (const float*)d_in[5];
  const float* b1    = (const float*)d_in[6];
  const float* g_in  = (const float*)d_in[7];
  const float* be_in = (const float*)d_in[8];
  const float* W2    = (const float*)d_in[9];
  const float* b2    = (const float*)d_in[10];
  const float* g_out = (const float*)d_in[11];
  const float* be_out= (const float*)d_in[12];
  const float* Wr1   = (const float*)d_in[13];
  const float* br1   = (const float*)d_in[14];
  const float* gr    = (const float*)d_in[15];
  const float* ber   = (const float*)d_in[16];
  const float* Wr2   = (const float*)d_in[17];
  const float* br2   = (const float*)d_in[18];
  float* out = (float*)d_out;

  const int N = in_sizes[0] / IN_F;   // 100000
  const int E = in_sizes[1] / 2;      // 1600000
  const int* srcv = ei;
  const int* dstv = ei + E;

  // workspace carve
  float* X0   = (float*)d_ws;                  // [N][128] fp32
  float* X1   = X0 + (size_t)N * HID;
  float* SKIP = X1 + (size_t)N * HID;
  int* colb    = (int*)(SKIP + (size_t)N * HID);
  int* row_ptr = colb + E;
  int* deg     = row_ptr + (N + 4);
  int* cursor  = deg + N;
  int* bsum    = cursor + N;
  int* boff    = bsum + 256;
  float* arena = (float*)(boff + 256);         // 17 slots x 640 floats
  ushort_t* WB = (ushort_t*)(arena + 17 * 640);// hi blob | lo blob (2*BLOBSZ ushorts)

  hipMemsetAsync(deg, 0, sizeof(int) * N, stream);
  hipMemsetAsync(SKIP, 0, sizeof(float) * (size_t)N * HID, stream);
  hipMemsetAsync(arena, 0, sizeof(float) * 17 * 640, stream);

  // CSR build
  hist_kernel<<<(E + 255) / 256, 256, 0, stream>>>(dstv, deg, E);
  int nbs = (N + 1023) / 1024;
  scan1_kernel<<<nbs, 256, 0, stream>>>(deg, bsum, N);
  scan2_kernel<<<1, 256, 0, stream>>>(bsum, boff, nbs, row_ptr, N, E);
  scan3_kernel<<<nbs, 256, 0, stream>>>(deg, boff, row_ptr, cursor, N);
  fill_kernel<<<(E + 255) / 256, 256, 0, stream>>>(srcv, dstv, cursor, colb, E);
  preconv_kernel<<<dim3(64, 17), 256, 0, stream>>>(W1_0, W1, W2, Wr1, WB);

  const int gg = (N + 127) / 128;
  const float invN = 1.0f / (float)N;
#define SLOT(s) (arena + (s) * 640)
#define SSUM(s) SLOT(s)
#define SSQ(s)  (SLOT(s) + 128)
#define SA(s)   (SLOT(s) + 256)
#define SC(s)   (SLOT(s) + 384)
#define SCNT(s) ((int*)(SLOT(s) + 512))
#define WBH(g)  (WB + ((g) == 0 ? 0 : (8192 + (size_t)((g) - 1) * 32768)))
#define WBL(g)  (WBH(g) + BLOBSZ)

  // ---- layer 0 ----  agg16: x -> X0[N,16]; g0a: X0 -> X1; g0b: X1 -> X1 in-place
  agg16_kernel<<<(N + 31) / 32, 256, 0, stream>>>(x, row_ptr, colb, eps, X0, N);
  gemm_mfma<32, 3><<<gg, 256, 0, stream>>>(
      X0, nullptr, WBH(0), WBL(0), b1_0, nullptr, nullptr, X1,
      SSUM(0), SSQ(0), SA(0), SC(0), SCNT(0), g_in, be_in, invN, N, gg);
  gemm_mfma<128, 1><<<gg, 256, 0, stream>>>(
      X1, nullptr, WBH(8), WBL(8), b2, SA(0), SC(0), X1,
      SSUM(1), SSQ(1), SA(1), SC(1), SCNT(1), g_out, be_out, invN, N, gg);
  // Y0 in X1

  // ---- layers 1..7 ----  agg: X1->X0; gemm1: X0->X0 (in place); gemm2: X0->X1
  for (int L = 1; L < NLAYERS; ++L) {
    int sp = 2 * L - 1;
    int s0 = 2 * L, s1 = 2 * L + 1;
    float* skipw = ((L - 1) & 1) ? SKIP : nullptr;  // fold h_{L-1} at L=2,4,6
    agg128_kernel<<<(N + 3) / 4, 256, 0, stream>>>(
        X1, SA(sp), SC(sp), row_ptr, colb, eps, L, X0, skipw, N);
    gemm_mfma<128, 0><<<gg, 256, 0, stream>>>(
        X0, nullptr, WBH(L), WBL(L), b1 + (size_t)(L - 1) * HID, nullptr, nullptr, X0,
        SSUM(s0), SSQ(s0), SA(s0), SC(s0), SCNT(s0),
        g_in + (size_t)L * HID, be_in + (size_t)L * HID, invN, N, gg);
    gemm_mfma<128, 1><<<gg, 256, 0, stream>>>(
        X0, nullptr, WBH(8 + L), WBL(8 + L), b2 + (size_t)L * HID, SA(s0), SC(s0), X1,
        SSUM(s1), SSQ(s1), SA(s1), SC(s1), SCNT(s1),
        g_out + (size_t)L * HID, be_out + (size_t)L * HID, invN, N, gg);
  }
  // Y7 in X1, slot 15 holds its outer-BN params

  // ---- regressor: op = 0.25*(SKIP + relu(a7*Y7+c7)) ----
  gemm_mfma<128, 2><<<gg, 256, 0, stream>>>(
      SKIP, X1, WBH(16), WBL(16), br1, SA(15), SC(15), X0,
      SSUM(16), SSQ(16), SA(16), SC(16), SCNT(16), gr, ber, invN, N, gg);
  finaldot_kernel<<<(N + 3) / 4, 256, 0, stream>>>(X0, SA(16), SC(16), Wr2, br2, out, N);
#undef SLOT
#undef SSUM
#undef SSQ
#undef SA
#undef SC
#undef SCNT
#undef WBH
#undef WBL
}

// Round 6
// 2242.024 us; speedup vs baseline: 1.1696x; 1.1696x over previous
//
#include <hip/hip_runtime.h>
#include <hip/hip_bf16.h>

#define NNODES 100000
#define NEDGES 1600000
#define IN_F 16
#define HID 128
#define NLAYERS 8
#define BN_EPS 1e-5f
#define BLOBSZ 532480   // ushorts per blob half: 8192 + 16*32768

typedef __attribute__((ext_vector_type(8))) short short8;
typedef __attribute__((ext_vector_type(4))) float f32x4;
typedef __attribute__((ext_vector_type(4))) unsigned int uint32x4;
typedef unsigned short ushort_t;
typedef unsigned int uint_t;

__device__ __forceinline__ ushort_t f2bf(float f) {
  uint_t u = __builtin_bit_cast(uint_t, f);
  uint_t r = (u + 0x7fffu + ((u >> 16) & 1u)) >> 16;
  return (ushort_t)r;
}
__device__ __forceinline__ float bfl(uint_t u) {
  return __builtin_bit_cast(float, u << 16);
}
// RNE split for weights (preconv, off critical path)
__device__ __forceinline__ void bsplit(float v, ushort_t& h, ushort_t& l) {
  h = f2bf(v);
  float r = v - bfl((uint_t)h);
  l = f2bf(r);
}

// cheap truncation split of 8 fp32 -> hi/lo short8 (err <= 2^-16 rel)
__device__ __forceinline__ void split8(const float* v, short8& h8, short8& l8) {
  uint_t hp[4], lp[4];
#pragma unroll
  for (int j = 0; j < 4; ++j) {
    float v0 = v[2 * j], v1 = v[2 * j + 1];
    uint_t u0 = __builtin_bit_cast(uint_t, v0);
    uint_t u1 = __builtin_bit_cast(uint_t, v1);
    uint_t h0 = u0 & 0xFFFF0000u;
    uint_t h1 = u1 & 0xFFFF0000u;
    float r0 = v0 - __builtin_bit_cast(float, h0);
    float r1 = v1 - __builtin_bit_cast(float, h1);
    hp[j] = (h0 >> 16) | h1;
    lp[j] = (__builtin_bit_cast(uint_t, r0) >> 16) |
            (__builtin_bit_cast(uint_t, r1) & 0xFFFF0000u);
  }
  h8 = __builtin_bit_cast(short8, (uint32x4){hp[0], hp[1], hp[2], hp[3]});
  l8 = __builtin_bit_cast(short8, (uint32x4){lp[0], lp[1], lp[2], lp[3]});
}

// ============================ CSR build ============================

__global__ void hist_kernel(const int* __restrict__ dst, int* __restrict__ deg, int E) {
  int i = blockIdx.x * blockDim.x + threadIdx.x;
  if (i < E) atomicAdd(&deg[dst[i]], 1);
}

__global__ void scan1_kernel(const int* __restrict__ deg, int* __restrict__ bsum, int N) {
  __shared__ int sdata[256];
  int b = blockIdx.x, t = threadIdx.x;
  int base = b * 1024 + t * 4;
  int s = 0;
#pragma unroll
  for (int j = 0; j < 4; ++j) {
    int i = base + j;
    if (i < N) s += deg[i];
  }
  sdata[t] = s;
  __syncthreads();
  for (int off = 128; off > 0; off >>= 1) {
    if (t < off) sdata[t] += sdata[t + off];
    __syncthreads();
  }
  if (t == 0) bsum[b] = sdata[0];
}

__global__ void scan2_kernel(const int* __restrict__ bsum, int* __restrict__ boff,
                             int nb, int* __restrict__ row_ptr, int N, int E) {
  __shared__ int s[256];
  int t = threadIdx.x;
  s[t] = (t < nb) ? bsum[t] : 0;
  __syncthreads();
  for (int off = 1; off < 256; off <<= 1) {
    int v = (t >= off) ? s[t - off] : 0;
    __syncthreads();
    s[t] += v;
    __syncthreads();
  }
  boff[t] = (t == 0) ? 0 : s[t - 1];
  if (t == 0) row_ptr[N] = E;
}

__global__ void scan3_kernel(const int* __restrict__ deg, const int* __restrict__ boff,
                             int* __restrict__ row_ptr, int* __restrict__ cursor, int N) {
  __shared__ int sdata[256];
  int b = blockIdx.x, t = threadIdx.x;
  int base = b * 1024 + t * 4;
  int v[4];
  int s = 0;
#pragma unroll
  for (int j = 0; j < 4; ++j) {
    int i = base + j;
    v[j] = (i < N) ? deg[i] : 0;
    s += v[j];
  }
  sdata[t] = s;
  __syncthreads();
  for (int off = 1; off < 256; off <<= 1) {
    int u = (t >= off) ? sdata[t - off] : 0;
    __syncthreads();
    sdata[t] += u;
    __syncthreads();
  }
  int excl = boff[b] + ((t == 0) ? 0 : sdata[t - 1]);
#pragma unroll
  for (int j = 0; j < 4; ++j) {
    int i = base + j;
    if (i < N) {
      row_ptr[i] = excl;
      cursor[i] = excl;
      excl += v[j];
    }
  }
}

__global__ void fill_kernel(const int* __restrict__ src, const int* __restrict__ dst,
                            int* __restrict__ cursor, int* __restrict__ colb, int E) {
  int i = blockIdx.x * blockDim.x + threadIdx.x;
  if (i < E) {
    int d = dst[i];
    int pos = atomicAdd(&cursor[d], 1);
    colb[pos] = src[i];
  }
}

// =================== weight pre-convert: split hi/lo MFMA-frag blobs ===================
__global__ void preconv_kernel(const float* __restrict__ W1_0, const float* __restrict__ W1,
                               const float* __restrict__ W2, const float* __restrict__ Wr1,
                               ushort_t* __restrict__ WB) {
  int g = blockIdx.y;
  int e = blockIdx.x * 256 + threadIdx.x;
  int KP = (g == 0) ? 32 : 128;
  if (e >= KP * 128) return;
  int k = e >> 7, n = e & 127;
  float v;
  if (g == 0) v = (k < 16) ? W1_0[k * 128 + n] : 0.0f;
  else if (g <= 7) v = W1[(size_t)(g - 1) * 16384 + e];
  else if (g <= 15) v = W2[(size_t)(g - 8) * 16384 + e];
  else v = Wr1[e];
  size_t base = (g == 0) ? 0 : (8192 + (size_t)(g - 1) * 32768);
  int unit = ((k >> 5) << 9) + ((n >> 4) << 6) + (n & 15) + (((k >> 3) & 3) << 4);
  ushort_t h, l;
  bsplit(v, h, l);
  WB[base + (size_t)unit * 8 + (k & 7)] = h;
  WB[BLOBSZ + base + (size_t)unit * 8 + (k & 7)] = l;
}

// ============================ Aggregation ============================

__global__ __launch_bounds__(256) void agg16_kernel(
    const float* __restrict__ X, const int* __restrict__ rp, const int* __restrict__ colb,
    const float* __restrict__ eps, float* __restrict__ Z, int N) {
  int g = threadIdx.x >> 3;
  int l = threadIdx.x & 7;
  int n = blockIdx.x * 32 + g;
  if (n >= N) return;
  float e = 1.0f + eps[0];
  const float2* X2 = (const float2*)X;
  float2 self = X2[(size_t)n * 8 + l];
  float2 acc = make_float2(self.x * e, self.y * e);
  float2 acc2 = make_float2(0.0f, 0.0f);
  int beg = rp[n], end = rp[n + 1];
  int p = beg;
  for (; p + 4 <= end; p += 4) {
    int s0 = colb[p], s1 = colb[p + 1], s2 = colb[p + 2], s3 = colb[p + 3];
    float2 v0 = X2[(size_t)s0 * 8 + l];
    float2 v1 = X2[(size_t)s1 * 8 + l];
    float2 v2 = X2[(size_t)s2 * 8 + l];
    float2 v3 = X2[(size_t)s3 * 8 + l];
    acc.x += v0.x; acc.y += v0.y;
    acc2.x += v1.x; acc2.y += v1.y;
    acc.x += v2.x; acc.y += v2.y;
    acc2.x += v3.x; acc2.y += v3.y;
  }
  for (; p < end; ++p) {
    int s = colb[p];
    float2 v = X2[(size_t)s * 8 + l];
    acc.x += v.x; acc.y += v.y;
  }
  acc.x += acc2.x; acc.y += acc2.y;
  ((float2*)Z)[(size_t)n * 8 + l] = acc;
}

// layers 1..7: fp32 Y, fused h=relu(a*y+c), SKIP += h(self), Z fp32
__global__ __launch_bounds__(256) void agg128_kernel(
    const float* __restrict__ Y, const float* __restrict__ av, const float* __restrict__ cv,
    const int* __restrict__ rp, const int* __restrict__ colb,
    const float* __restrict__ eps, int layer, float* __restrict__ Z,
    float* __restrict__ SKIP, int N) {
  int wv = threadIdx.x >> 6;
  int lane = threadIdx.x & 63;
  int n = blockIdx.x * 4 + wv;
  if (n >= N) return;
  float e = 1.0f + eps[layer];
  float2 a2 = *(const float2*)(av + lane * 2);
  float2 c2 = *(const float2*)(cv + lane * 2);
  const float2* Y2 = (const float2*)Y;
  float2 sv = Y2[(size_t)n * 64 + lane];
  float hx = fmaxf(fmaf(a2.x, sv.x, c2.x), 0.0f);
  float hy = fmaxf(fmaf(a2.y, sv.y, c2.y), 0.0f);
  if (SKIP) {
    float2* S2 = (float2*)SKIP;
    float2 s = S2[(size_t)n * 64 + lane];
    s.x += hx; s.y += hy;
    S2[(size_t)n * 64 + lane] = s;
  }
  float ax = hx * e, ay = hy * e;
  float bx = 0.0f, by = 0.0f, cx = 0.0f, cy = 0.0f, dx = 0.0f, dy = 0.0f;
  int beg = rp[n], end = rp[n + 1];
  int p = beg;
  for (; p + 8 <= end; p += 8) {
    int s0 = colb[p], s1 = colb[p + 1], s2 = colb[p + 2], s3 = colb[p + 3];
    int s4 = colb[p + 4], s5 = colb[p + 5], s6 = colb[p + 6], s7 = colb[p + 7];
    float2 v0 = Y2[(size_t)s0 * 64 + lane];
    float2 v1 = Y2[(size_t)s1 * 64 + lane];
    float2 v2 = Y2[(size_t)s2 * 64 + lane];
    float2 v3 = Y2[(size_t)s3 * 64 + lane];
    float2 v4 = Y2[(size_t)s4 * 64 + lane];
    float2 v5 = Y2[(size_t)s5 * 64 + lane];
    float2 v6 = Y2[(size_t)s6 * 64 + lane];
    float2 v7 = Y2[(size_t)s7 * 64 + lane];
    ax += fmaxf(fmaf(a2.x, v0.x, c2.x), 0.0f);
    ay += fmaxf(fmaf(a2.y, v0.y, c2.y), 0.0f);
    bx += fmaxf(fmaf(a2.x, v1.x, c2.x), 0.0f);
    by += fmaxf(fmaf(a2.y, v1.y, c2.y), 0.0f);
    cx += fmaxf(fmaf(a2.x, v2.x, c2.x), 0.0f);
    cy += fmaxf(fmaf(a2.y, v2.y, c2.y), 0.0f);
    dx += fmaxf(fmaf(a2.x, v3.x, c2.x), 0.0f);
    dy += fmaxf(fmaf(a2.y, v3.y, c2.y), 0.0f);
    ax += fmaxf(fmaf(a2.x, v4.x, c2.x), 0.0f);
    ay += fmaxf(fmaf(a2.y, v4.y, c2.y), 0.0f);
    bx += fmaxf(fmaf(a2.x, v5.x, c2.x), 0.0f);
    by += fmaxf(fmaf(a2.y, v5.y, c2.y), 0.0f);
    cx += fmaxf(fmaf(a2.x, v6.x, c2.x), 0.0f);
    cy += fmaxf(fmaf(a2.y, v6.y, c2.y), 0.0f);
    dx += fmaxf(fmaf(a2.x, v7.x, c2.x), 0.0f);
    dy += fmaxf(fmaf(a2.y, v7.y, c2.y), 0.0f);
  }
  for (; p < end; ++p) {
    int s = colb[p];
    float2 v = Y2[(size_t)s * 64 + lane];
    ax += fmaxf(fmaf(a2.x, v.x, c2.x), 0.0f);
    ay += fmaxf(fmaf(a2.y, v.y, c2.y), 0.0f);
  }
  ax += bx + cx + dx;
  ay += by + cy + dy;
  ((float2*)Z)[(size_t)n * 64 + lane] = make_float2(ax, ay);
}

// ============================ LDS-free split-bf16 MFMA GEMM ============================
// C(fp32)[M,128] = op(A)[M,K] @ B + bias via A_hi*B_hi + A_lo*B_hi + A_hi*B_lo.
// No LDS staging, no barriers in the K loop.
// Epilogue publication: plain relaxed device-scope atomics ONLY — no __threadfence,
// no acq_rel (those emit buffer_wbl2/buffer_inv = full per-XCD L2 flush per block,
// which was pinning every GEMM at ~85-90 us regardless of inner-loop structure).
// Ordering argument: __syncthreads() drains vmcnt(0) per wave (m97 asm), so all
// stats atomics are complete (hence LLC-visible) before the relaxed election;
// the elected last block re-reads stats with agent-scope relaxed atomic loads.
// MODE 0: op=A   MODE 1: op=relu(pa*A+pc)   MODE 2: op=0.25*(A + relu(pa*A2+pc))
// MODE 3: A fp32 [M,16], K=32 zero-padded (blob rows 16..31 pre-zeroed)
template <int KTOT, int MODE>
__global__ __launch_bounds__(256, 4) void gemm_mfma(
    const float* __restrict__ A, const float* __restrict__ A2f,
    const ushort_t* __restrict__ Bhi, const ushort_t* __restrict__ Blo,
    const float* __restrict__ bias,
    const float* __restrict__ pa, const float* __restrict__ pc,
    float* __restrict__ C,
    float* __restrict__ gsum, float* __restrict__ gsq,
    float* __restrict__ aout, float* __restrict__ cout, int* __restrict__ cnt,
    const float* __restrict__ gamma, const float* __restrict__ beta,
    float invN, int M, int nb) {
  __shared__ float s_sum[128];
  __shared__ float s_sq[128];
  __shared__ int s_last;
  const int tid = threadIdx.x;
  const int w = tid >> 6;
  const int lane = tid & 63;
  const int ln = lane & 15;
  const int quad = lane >> 4;
  const int brow = blockIdx.x * 128;
  constexpr int AST = (MODE == 3) ? 16 : KTOT;  // A row stride (fp32 elems)

  int r0 = brow + (w << 5) + ln;       if (r0 >= M) r0 = M - 1;
  int r1 = brow + (w << 5) + 16 + ln;  if (r1 >= M) r1 = M - 1;

  f32x4 acc[2][8];
#pragma unroll
  for (int rt = 0; rt < 2; ++rt)
#pragma unroll
    for (int ct = 0; ct < 8; ++ct) acc[rt][ct] = (f32x4){0.0f, 0.0f, 0.0f, 0.0f};

  constexpr int KC = KTOT / 32;
#pragma unroll
  for (int kcl = 0; kcl < KC; ++kcl) {
    const int kb = (kcl << 5) + (quad << 3);
    float e0[8], e1[8];
    if constexpr (MODE == 3) {
      if (kb < 16) {
        float4 a0 = *(const float4*)(A + (size_t)r0 * AST + kb);
        float4 a1 = *(const float4*)(A + (size_t)r0 * AST + kb + 4);
        e0[0] = a0.x; e0[1] = a0.y; e0[2] = a0.z; e0[3] = a0.w;
        e0[4] = a1.x; e0[5] = a1.y; e0[6] = a1.z; e0[7] = a1.w;
        float4 b0 = *(const float4*)(A + (size_t)r1 * AST + kb);
        float4 b1 = *(const float4*)(A + (size_t)r1 * AST + kb + 4);
        e1[0] = b0.x; e1[1] = b0.y; e1[2] = b0.z; e1[3] = b0.w;
        e1[4] = b1.x; e1[5] = b1.y; e1[6] = b1.z; e1[7] = b1.w;
      } else {
#pragma unroll
        for (int j = 0; j < 8; ++j) { e0[j] = 0.0f; e1[j] = 0.0f; }
      }
    } else {
      float4 a0 = *(const float4*)(A + (size_t)r0 * AST + kb);
      float4 a1 = *(const float4*)(A + (size_t)r0 * AST + kb + 4);
      float4 b0 = *(const float4*)(A + (size_t)r1 * AST + kb);
      float4 b1 = *(const float4*)(A + (size_t)r1 * AST + kb + 4);
      e0[0] = a0.x; e0[1] = a0.y; e0[2] = a0.z; e0[3] = a0.w;
      e0[4] = a1.x; e0[5] = a1.y; e0[6] = a1.z; e0[7] = a1.w;
      e1[0] = b0.x; e1[1] = b0.y; e1[2] = b0.z; e1[3] = b0.w;
      e1[4] = b1.x; e1[5] = b1.y; e1[6] = b1.z; e1[7] = b1.w;
      if constexpr (MODE == 1) {
        float4 p0 = *(const float4*)(pa + kb);
        float4 p1 = *(const float4*)(pa + kb + 4);
        float4 q0 = *(const float4*)(pc + kb);
        float4 q1 = *(const float4*)(pc + kb + 4);
        float pp[8] = {p0.x, p0.y, p0.z, p0.w, p1.x, p1.y, p1.z, p1.w};
        float qq[8] = {q0.x, q0.y, q0.z, q0.w, q1.x, q1.y, q1.z, q1.w};
#pragma unroll
        for (int j = 0; j < 8; ++j) {
          e0[j] = fmaxf(fmaf(pp[j], e0[j], qq[j]), 0.0f);
          e1[j] = fmaxf(fmaf(pp[j], e1[j], qq[j]), 0.0f);
        }
      } else if constexpr (MODE == 2) {
        float4 y00 = *(const float4*)(A2f + (size_t)r0 * AST + kb);
        float4 y01 = *(const float4*)(A2f + (size_t)r0 * AST + kb + 4);
        float4 y10 = *(const float4*)(A2f + (size_t)r1 * AST + kb);
        float4 y11 = *(const float4*)(A2f + (size_t)r1 * AST + kb + 4);
        float4 p0 = *(const float4*)(pa + kb);
        float4 p1 = *(const float4*)(pa + kb + 4);
        float4 q0 = *(const float4*)(pc + kb);
        float4 q1 = *(const float4*)(pc + kb + 4);
        float y0a[8] = {y00.x, y00.y, y00.z, y00.w, y01.x, y01.y, y01.z, y01.w};
        float y1a[8] = {y10.x, y10.y, y10.z, y10.w, y11.x, y11.y, y11.z, y11.w};
        float pp[8] = {p0.x, p0.y, p0.z, p0.w, p1.x, p1.y, p1.z, p1.w};
        float qq[8] = {q0.x, q0.y, q0.z, q0.w, q1.x, q1.y, q1.z, q1.w};
#pragma unroll
        for (int j = 0; j < 8; ++j) {
          e0[j] = 0.25f * (e0[j] + fmaxf(fmaf(pp[j], y0a[j], qq[j]), 0.0f));
          e1[j] = 0.25f * (e1[j] + fmaxf(fmaf(pp[j], y1a[j], qq[j]), 0.0f));
        }
      }
    }
    short8 a0h, a0l, a1h, a1l;
    split8(e0, a0h, a0l);
    split8(e1, a1h, a1l);
    const ushort_t* bh_base = Bhi + (((size_t)(kcl << 9) + lane) << 3);
    const ushort_t* bl_base = Blo + (((size_t)(kcl << 9) + lane) << 3);
#pragma unroll
    for (int ct = 0; ct < 8; ++ct) {
      short8 bh = *(const short8*)(bh_base + (ct << 9));
      short8 bl = *(const short8*)(bl_base + (ct << 9));
      acc[0][ct] = __builtin_amdgcn_mfma_f32_16x16x32_bf16(a0h, bh, acc[0][ct], 0, 0, 0);
      acc[0][ct] = __builtin_amdgcn_mfma_f32_16x16x32_bf16(a0l, bh, acc[0][ct], 0, 0, 0);
      acc[0][ct] = __builtin_amdgcn_mfma_f32_16x16x32_bf16(a0h, bl, acc[0][ct], 0, 0, 0);
      acc[1][ct] = __builtin_amdgcn_mfma_f32_16x16x32_bf16(a1h, bh, acc[1][ct], 0, 0, 0);
      acc[1][ct] = __builtin_amdgcn_mfma_f32_16x16x32_bf16(a1l, bh, acc[1][ct], 0, 0, 0);
      acc[1][ct] = __builtin_amdgcn_mfma_f32_16x16x32_bf16(a1h, bl, acc[1][ct], 0, 0, 0);
    }
  }

  // ---- epilogue: bias, stats, fp32 store ----
  if (tid < 128) { s_sum[tid] = 0.0f; s_sq[tid] = 0.0f; }
  __syncthreads();
#pragma unroll
  for (int ct = 0; ct < 8; ++ct) {
    int col = (ct << 4) + ln;
    float bsc = bias[col];
    float csum = 0.0f, csq = 0.0f;
#pragma unroll
    for (int rt = 0; rt < 2; ++rt) {
#pragma unroll
      for (int i = 0; i < 4; ++i) {
        int row = brow + (w << 5) + (rt << 4) + (quad << 2) + i;
        if (row < M) {
          float y = acc[rt][ct][i] + bsc;
          csum += y; csq += y * y;
          C[(size_t)row * 128 + col] = y;
        }
      }
    }
    atomicAdd(&s_sum[col], csum);
    atomicAdd(&s_sq[col], csq);
  }
  __syncthreads();
  if (tid < 128) {
    atomicAdd(&gsum[tid], s_sum[tid]);   // relaxed device-scope, no flush
    atomicAdd(&gsq[tid], s_sq[tid]);
  }
  __syncthreads();   // drains vmcnt(0) per wave -> all stats atomics complete
  if (tid == 0) {
    int v = __hip_atomic_fetch_add(cnt, 1, __ATOMIC_RELAXED, __HIP_MEMORY_SCOPE_AGENT);
    s_last = (v == nb - 1) ? 1 : 0;
  }
  __syncthreads();
  if (s_last && tid < 128) {
    float s = __hip_atomic_load(&gsum[tid], __ATOMIC_RELAXED, __HIP_MEMORY_SCOPE_AGENT);
    float q = __hip_atomic_load(&gsq[tid], __ATOMIC_RELAXED, __HIP_MEMORY_SCOPE_AGENT);
    float mu = s * invN;
    float var = q * invN - mu * mu;
    float sc = gamma[tid] * rsqrtf(var + BN_EPS);
    aout[tid] = sc;
    cout[tid] = beta[tid] - sc * mu;
  }
}

// ============================ regressor head ============================
__global__ __launch_bounds__(256) void finaldot_kernel(
    const float* __restrict__ Y, const float* __restrict__ a, const float* __restrict__ c,
    const float* __restrict__ Wr2, const float* __restrict__ br2,
    float* __restrict__ out, int N) {
  int wv = threadIdx.x >> 6;
  int lane = threadIdx.x & 63;
  int n = blockIdx.x * 4 + wv;
  if (n >= N) return;
  float2 y = *(const float2*)(Y + (size_t)n * HID + lane * 2);
  int c0 = lane * 2;
  float s = fmaxf(fmaf(a[c0], y.x, c[c0]), 0.0f) * Wr2[c0] +
            fmaxf(fmaf(a[c0 + 1], y.y, c[c0 + 1]), 0.0f) * Wr2[c0 + 1];
  for (int off = 32; off > 0; off >>= 1) s += __shfl_down(s, off, 64);
  if (lane == 0) out[n] = 1.0f / (1.0f + expf(-(s + br2[0])));
}

// ============================ launch ============================
extern "C" void kernel_launch(void* const* d_in, const int* in_sizes, int n_in,
                              void* d_out, int out_size, void* d_ws, size_t ws_size,
                              hipStream_t stream) {
  const float* x     = (const float*)d_in[0];
  const int*   ei    = (const int*)d_in[1];
  const float* eps   = (const float*)d_in[2];
  const float* W1_0  = (const float*)d_in[3];
  const float* b1_0  = (const float*)d_in[4];
  const float* W1    = (const float*)d_in[5];
  const float* b1    = (const float*)d_in[6];
  const float* g_in  = (const float*)d_in[7];
  const float* be_in = (const float*)d_in[8];
  const float* W2    = (const float*)d_in[9];
  const float* b2    = (const float*)d_in[10];
  const float* g_out = (const float*)d_in[11];
  const float* be_out= (const float*)d_in[12];
  const float* Wr1   = (const float*)d_in[13];
  const float* br1   = (const float*)d_in[14];
  const float* gr    = (const float*)d_in[15];
  const float* ber   = (const float*)d_in[16];
  const float* Wr2   = (const float*)d_in[17];
  const float* br2   = (const float*)d_in[18];
  float* out = (float*)d_out;

  const int N = in_sizes[0] / IN_F;   // 100000
  const int E = in_sizes[1] / 2;      // 1600000
  const int* srcv = ei;
  const int* dstv = ei + E;

  // workspace carve
  float* X0   = (float*)d_ws;                  // [N][128] fp32
  float* X1   = X0 + (size_t)N * HID;
  float* SKIP = X1 + (size_t)N * HID;
  int* colb    = (int*)(SKIP + (size_t)N * HID);
  int* row_ptr = colb + E;
  int* deg     = row_ptr + (N + 4);
  int* cursor  = deg + N;
  int* bsum    = cursor + N;
  int* boff    = bsum + 256;
  float* arena = (float*)(boff + 256);         // 17 slots x 640 floats
  ushort_t* WB = (ushort_t*)(arena + 17 * 640);// hi blob | lo blob (2*BLOBSZ ushorts)

  hipMemsetAsync(deg, 0, sizeof(int) * N, stream);
  hipMemsetAsync(SKIP, 0, sizeof(float) * (size_t)N * HID, stream);
  hipMemsetAsync(arena, 0, sizeof(float) * 17 * 640, stream);

  // CSR build
  hist_kernel<<<(E + 255) / 256, 256, 0, stream>>>(dstv, deg, E);
  int nbs = (N + 1023) / 1024;
  scan1_kernel<<<nbs, 256, 0, stream>>>(deg, bsum, N);
  scan2_kernel<<<1, 256, 0, stream>>>(bsum, boff, nbs, row_ptr, N, E);
  scan3_kernel<<<nbs, 256, 0, stream>>>(deg, boff, row_ptr, cursor, N);
  fill_kernel<<<(E + 255) / 256, 256, 0, stream>>>(srcv, dstv, cursor, colb, E);
  preconv_kernel<<<dim3(64, 17), 256, 0, stream>>>(W1_0, W1, W2, Wr1, WB);

  const int gg = (N + 127) / 128;
  const float invN = 1.0f / (float)N;
#define SLOT(s) (arena + (s) * 640)
#define SSUM(s) SLOT(s)
#define SSQ(s)  (SLOT(s) + 128)
#define SA(s)   (SLOT(s) + 256)
#define SC(s)   (SLOT(s) + 384)
#define SCNT(s) ((int*)(SLOT(s) + 512))
#define WBH(g)  (WB + ((g) == 0 ? 0 : (8192 + (size_t)((g) - 1) * 32768)))
#define WBL(g)  (WBH(g) + BLOBSZ)

  // ---- layer 0 ----  agg16: x -> X0[N,16]; g0a: X0 -> X1; g0b: X1 -> X1 in-place
  agg16_kernel<<<(N + 31) / 32, 256, 0, stream>>>(x, row_ptr, colb, eps, X0, N);
  gemm_mfma<32, 3><<<gg, 256, 0, stream>>>(
      X0, nullptr, WBH(0), WBL(0), b1_0, nullptr, nullptr, X1,
      SSUM(0), SSQ(0), SA(0), SC(0), SCNT(0), g_in, be_in, invN, N, gg);
  gemm_mfma<128, 1><<<gg, 256, 0, stream>>>(
      X1, nullptr, WBH(8), WBL(8), b2, SA(0), SC(0), X1,
      SSUM(1), SSQ(1), SA(1), SC(1), SCNT(1), g_out, be_out, invN, N, gg);
  // Y0 in X1

  // ---- layers 1..7 ----  agg: X1->X0; gemm1: X0->X0 (in place); gemm2: X0->X1
  for (int L = 1; L < NLAYERS; ++L) {
    int sp = 2 * L - 1;
    int s0 = 2 * L, s1 = 2 * L + 1;
    float* skipw = ((L - 1) & 1) ? SKIP : nullptr;  // fold h_{L-1} at L=2,4,6
    agg128_kernel<<<(N + 3) / 4, 256, 0, stream>>>(
        X1, SA(sp), SC(sp), row_ptr, colb, eps, L, X0, skipw, N);
    gemm_mfma<128, 0><<<gg, 256, 0, stream>>>(
        X0, nullptr, WBH(L), WBL(L), b1 + (size_t)(L - 1) * HID, nullptr, nullptr, X0,
        SSUM(s0), SSQ(s0), SA(s0), SC(s0), SCNT(s0),
        g_in + (size_t)L * HID, be_in + (size_t)L * HID, invN, N, gg);
    gemm_mfma<128, 1><<<gg, 256, 0, stream>>>(
        X0, nullptr, WBH(8 + L), WBL(8 + L), b2 + (size_t)L * HID, SA(s0), SC(s0), X1,
        SSUM(s1), SSQ(s1), SA(s1), SC(s1), SCNT(s1),
        g_out + (size_t)L * HID, be_out + (size_t)L * HID, invN, N, gg);
  }
  // Y7 in X1, slot 15 holds its outer-BN params

  // ---- regressor: op = 0.25*(SKIP + relu(a7*Y7+c7)) ----
  gemm_mfma<128, 2><<<gg, 256, 0, stream>>>(
      SKIP, X1, WBH(16), WBL(16), br1, SA(15), SC(15), X0,
      SSUM(16), SSQ(16), SA(16), SC(16), SCNT(16), gr, ber, invN, N, gg);
  finaldot_kernel<<<(N + 3) / 4, 256, 0, stream>>>(X0, SA(16), SC(16), Wr2, br2, out, N);
#undef SLOT
#undef SSUM
#undef SSQ
#undef SA
#undef SC
#undef SCNT
#undef WBH
#undef WBL
}

// Round 7
// 1974.215 us; speedup vs baseline: 1.3282x; 1.1357x over previous
//
#include <hip/hip_runtime.h>
#include <hip/hip_bf16.h>

#define NNODES 100000
#define NEDGES 1600000
#define IN_F 16
#define HID 128
#define NLAYERS 8
#define BN_EPS 1e-5f
#define BLOBSZ 532480   // ushorts per blob half: 8192 + 16*32768

typedef __attribute__((ext_vector_type(8))) short short8;
typedef __attribute__((ext_vector_type(4))) float f32x4;
typedef __attribute__((ext_vector_type(4))) unsigned int uint32x4;
typedef unsigned short ushort_t;
typedef unsigned int uint_t;

__device__ __forceinline__ ushort_t f2bf(float f) {   // RNE, unbiased
  uint_t u = __builtin_bit_cast(uint_t, f);
  uint_t r = (u + 0x7fffu + ((u >> 16) & 1u)) >> 16;
  return (ushort_t)r;
}
__device__ __forceinline__ float bfl(uint_t u) {
  return __builtin_bit_cast(float, u << 16);
}
__device__ __forceinline__ float bfh(uint_t u) {
  return __builtin_bit_cast(float, u & 0xFFFF0000u);
}
// RNE split for weights (preconv, off critical path)
__device__ __forceinline__ void bsplit(float v, ushort_t& h, ushort_t& l) {
  h = f2bf(v);
  float r = v - bfl((uint_t)h);
  l = f2bf(r);
}

// cheap truncation split of 8 fp32 -> hi/lo short8 (err <= 2^-16 rel)
__device__ __forceinline__ void split8(const float* v, short8& h8, short8& l8) {
  uint_t hp[4], lp[4];
#pragma unroll
  for (int j = 0; j < 4; ++j) {
    float v0 = v[2 * j], v1 = v[2 * j + 1];
    uint_t u0 = __builtin_bit_cast(uint_t, v0);
    uint_t u1 = __builtin_bit_cast(uint_t, v1);
    uint_t h0 = u0 & 0xFFFF0000u;
    uint_t h1 = u1 & 0xFFFF0000u;
    float r0 = v0 - __builtin_bit_cast(float, h0);
    float r1 = v1 - __builtin_bit_cast(float, h1);
    hp[j] = (h0 >> 16) | h1;
    lp[j] = (__builtin_bit_cast(uint_t, r0) >> 16) |
            (__builtin_bit_cast(uint_t, r1) & 0xFFFF0000u);
  }
  h8 = __builtin_bit_cast(short8, (uint32x4){hp[0], hp[1], hp[2], hp[3]});
  l8 = __builtin_bit_cast(short8, (uint32x4){lp[0], lp[1], lp[2], lp[3]});
}

// ============================ CSR build ============================

__global__ void hist_kernel(const int* __restrict__ dst, int* __restrict__ deg, int E) {
  int i = blockIdx.x * blockDim.x + threadIdx.x;
  if (i < E) atomicAdd(&deg[dst[i]], 1);
}

__global__ void scan1_kernel(const int* __restrict__ deg, int* __restrict__ bsum, int N) {
  __shared__ int sdata[256];
  int b = blockIdx.x, t = threadIdx.x;
  int base = b * 1024 + t * 4;
  int s = 0;
#pragma unroll
  for (int j = 0; j < 4; ++j) {
    int i = base + j;
    if (i < N) s += deg[i];
  }
  sdata[t] = s;
  __syncthreads();
  for (int off = 128; off > 0; off >>= 1) {
    if (t < off) sdata[t] += sdata[t + off];
    __syncthreads();
  }
  if (t == 0) bsum[b] = sdata[0];
}

__global__ void scan2_kernel(const int* __restrict__ bsum, int* __restrict__ boff,
                             int nb, int* __restrict__ row_ptr, int N, int E) {
  __shared__ int s[256];
  int t = threadIdx.x;
  s[t] = (t < nb) ? bsum[t] : 0;
  __syncthreads();
  for (int off = 1; off < 256; off <<= 1) {
    int v = (t >= off) ? s[t - off] : 0;
    __syncthreads();
    s[t] += v;
    __syncthreads();
  }
  boff[t] = (t == 0) ? 0 : s[t - 1];
  if (t == 0) row_ptr[N] = E;
}

__global__ void scan3_kernel(const int* __restrict__ deg, const int* __restrict__ boff,
                             int* __restrict__ row_ptr, int* __restrict__ cursor, int N) {
  __shared__ int sdata[256];
  int b = blockIdx.x, t = threadIdx.x;
  int base = b * 1024 + t * 4;
  int v[4];
  int s = 0;
#pragma unroll
  for (int j = 0; j < 4; ++j) {
    int i = base + j;
    v[j] = (i < N) ? deg[i] : 0;
    s += v[j];
  }
  sdata[t] = s;
  __syncthreads();
  for (int off = 1; off < 256; off <<= 1) {
    int u = (t >= off) ? sdata[t - off] : 0;
    __syncthreads();
    sdata[t] += u;
    __syncthreads();
  }
  int excl = boff[b] + ((t == 0) ? 0 : sdata[t - 1]);
#pragma unroll
  for (int j = 0; j < 4; ++j) {
    int i = base + j;
    if (i < N) {
      row_ptr[i] = excl;
      cursor[i] = excl;
      excl += v[j];
    }
  }
}

__global__ void fill_kernel(const int* __restrict__ src, const int* __restrict__ dst,
                            int* __restrict__ cursor, int* __restrict__ colb, int E) {
  int i = blockIdx.x * blockDim.x + threadIdx.x;
  if (i < E) {
    int d = dst[i];
    int pos = atomicAdd(&cursor[d], 1);
    colb[pos] = src[i];
  }
}

// =================== weight pre-convert: split hi/lo MFMA-frag blobs ===================
__global__ void preconv_kernel(const float* __restrict__ W1_0, const float* __restrict__ W1,
                               const float* __restrict__ W2, const float* __restrict__ Wr1,
                               ushort_t* __restrict__ WB) {
  int g = blockIdx.y;
  int e = blockIdx.x * 256 + threadIdx.x;
  int KP = (g == 0) ? 32 : 128;
  if (e >= KP * 128) return;
  int k = e >> 7, n = e & 127;
  float v;
  if (g == 0) v = (k < 16) ? W1_0[k * 128 + n] : 0.0f;
  else if (g <= 7) v = W1[(size_t)(g - 1) * 16384 + e];
  else if (g <= 15) v = W2[(size_t)(g - 8) * 16384 + e];
  else v = Wr1[e];
  size_t base = (g == 0) ? 0 : (8192 + (size_t)(g - 1) * 32768);
  int unit = ((k >> 5) << 9) + ((n >> 4) << 6) + (n & 15) + (((k >> 3) & 3) << 4);
  ushort_t h, l;
  bsplit(v, h, l);
  WB[base + (size_t)unit * 8 + (k & 7)] = h;
  WB[BLOBSZ + base + (size_t)unit * 8 + (k & 7)] = l;
}

// ============================ Aggregation ============================

__global__ __launch_bounds__(256) void agg16_kernel(
    const float* __restrict__ X, const int* __restrict__ rp, const int* __restrict__ colb,
    const float* __restrict__ eps, float* __restrict__ Z, int N) {
  int g = threadIdx.x >> 3;
  int l = threadIdx.x & 7;
  int n = blockIdx.x * 32 + g;
  if (n >= N) return;
  float e = 1.0f + eps[0];
  const float2* X2 = (const float2*)X;
  float2 self = X2[(size_t)n * 8 + l];
  float2 acc = make_float2(self.x * e, self.y * e);
  float2 acc2 = make_float2(0.0f, 0.0f);
  int beg = rp[n], end = rp[n + 1];
  int p = beg;
  for (; p + 4 <= end; p += 4) {
    int s0 = colb[p], s1 = colb[p + 1], s2 = colb[p + 2], s3 = colb[p + 3];
    float2 v0 = X2[(size_t)s0 * 8 + l];
    float2 v1 = X2[(size_t)s1 * 8 + l];
    float2 v2 = X2[(size_t)s2 * 8 + l];
    float2 v3 = X2[(size_t)s3 * 8 + l];
    acc.x += v0.x; acc.y += v0.y;
    acc2.x += v1.x; acc2.y += v1.y;
    acc.x += v2.x; acc.y += v2.y;
    acc2.x += v3.x; acc2.y += v3.y;
  }
  for (; p < end; ++p) {
    int s = colb[p];
    float2 v = X2[(size_t)s * 8 + l];
    acc.x += v.x; acc.y += v.y;
  }
  acc.x += acc2.x; acc.y += acc2.y;
  ((float2*)Z)[(size_t)n * 8 + l] = acc;
}

// layers 1..7: Y bf16 [N][128], fused h=relu(a*y+c), SKIP(fp32) += h(self), Z fp32.
// One uint (2 bf16) per lane per row -> wave reads 256 B contiguous per row.
__global__ __launch_bounds__(256) void agg128_kernel(
    const ushort_t* __restrict__ Y, const float* __restrict__ av, const float* __restrict__ cv,
    const int* __restrict__ rp, const int* __restrict__ colb,
    const float* __restrict__ eps, int layer, float* __restrict__ Z,
    float* __restrict__ SKIP, int N) {
  int wv = threadIdx.x >> 6;
  int lane = threadIdx.x & 63;
  int n = blockIdx.x * 4 + wv;
  if (n >= N) return;
  float e = 1.0f + eps[layer];
  float2 a2 = *(const float2*)(av + lane * 2);
  float2 c2 = *(const float2*)(cv + lane * 2);
  const uint_t* Yu = (const uint_t*)Y;
  uint_t sv = Yu[(size_t)n * 64 + lane];
  float hx = fmaxf(fmaf(a2.x, bfl(sv), c2.x), 0.0f);
  float hy = fmaxf(fmaf(a2.y, bfh(sv), c2.y), 0.0f);
  if (SKIP) {
    float2* S2 = (float2*)SKIP;
    float2 s = S2[(size_t)n * 64 + lane];
    s.x += hx; s.y += hy;
    S2[(size_t)n * 64 + lane] = s;
  }
  float ax = hx * e, ay = hy * e;
  float bx = 0.0f, by = 0.0f, cx = 0.0f, cy = 0.0f, dx = 0.0f, dy = 0.0f;
  int beg = rp[n], end = rp[n + 1];
  int p = beg;
  for (; p + 8 <= end; p += 8) {
    int s0 = colb[p], s1 = colb[p + 1], s2 = colb[p + 2], s3 = colb[p + 3];
    int s4 = colb[p + 4], s5 = colb[p + 5], s6 = colb[p + 6], s7 = colb[p + 7];
    uint_t v0 = Yu[(size_t)s0 * 64 + lane];
    uint_t v1 = Yu[(size_t)s1 * 64 + lane];
    uint_t v2 = Yu[(size_t)s2 * 64 + lane];
    uint_t v3 = Yu[(size_t)s3 * 64 + lane];
    uint_t v4 = Yu[(size_t)s4 * 64 + lane];
    uint_t v5 = Yu[(size_t)s5 * 64 + lane];
    uint_t v6 = Yu[(size_t)s6 * 64 + lane];
    uint_t v7 = Yu[(size_t)s7 * 64 + lane];
    ax += fmaxf(fmaf(a2.x, bfl(v0), c2.x), 0.0f);
    ay += fmaxf(fmaf(a2.y, bfh(v0), c2.y), 0.0f);
    bx += fmaxf(fmaf(a2.x, bfl(v1), c2.x), 0.0f);
    by += fmaxf(fmaf(a2.y, bfh(v1), c2.y), 0.0f);
    cx += fmaxf(fmaf(a2.x, bfl(v2), c2.x), 0.0f);
    cy += fmaxf(fmaf(a2.y, bfh(v2), c2.y), 0.0f);
    dx += fmaxf(fmaf(a2.x, bfl(v3), c2.x), 0.0f);
    dy += fmaxf(fmaf(a2.y, bfh(v3), c2.y), 0.0f);
    ax += fmaxf(fmaf(a2.x, bfl(v4), c2.x), 0.0f);
    ay += fmaxf(fmaf(a2.y, bfh(v4), c2.y), 0.0f);
    bx += fmaxf(fmaf(a2.x, bfl(v5), c2.x), 0.0f);
    by += fmaxf(fmaf(a2.y, bfh(v5), c2.y), 0.0f);
    cx += fmaxf(fmaf(a2.x, bfl(v6), c2.x), 0.0f);
    cy += fmaxf(fmaf(a2.y, bfh(v6), c2.y), 0.0f);
    dx += fmaxf(fmaf(a2.x, bfl(v7), c2.x), 0.0f);
    dy += fmaxf(fmaf(a2.y, bfh(v7), c2.y), 0.0f);
  }
  for (; p < end; ++p) {
    int s = colb[p];
    uint_t v = Yu[(size_t)s * 64 + lane];
    ax += fmaxf(fmaf(a2.x, bfl(v), c2.x), 0.0f);
    ay += fmaxf(fmaf(a2.y, bfh(v), c2.y), 0.0f);
  }
  ax += bx + cx + dx;
  ay += by + cy + dy;
  ((float2*)Z)[(size_t)n * 64 + lane] = make_float2(ax, ay);
}

// ============================ LDS-free split-bf16 MFMA GEMM ============================
// C = op(A)[M,K] @ B + bias via A_hi*B_hi + A_lo*B_hi + A_hi*B_lo. No LDS/barriers in K loop.
// Epilogue publication: relaxed atomics only (no threadfence / acq_rel -> no L2 flush; r6 win).
// MODE 0: op=A(fp32)   MODE 1: op=relu(pa*A+pc), A fp32
// MODE 2: op=0.25*(A(fp32 SKIP) + relu(pa*A2(bf16)+pc))
// MODE 3: A fp32 [M,16], K=32 zero-padded
// OUT 0: C fp32     OUT 1: C bf16 (RNE) — stats still from exact fp32 accumulators
template <int KTOT, int MODE, int OUT>
__global__ __launch_bounds__(256, 4) void gemm_mfma(
    const float* __restrict__ A, const ushort_t* __restrict__ A2u,
    const ushort_t* __restrict__ Bhi, const ushort_t* __restrict__ Blo,
    const float* __restrict__ bias,
    const float* __restrict__ pa, const float* __restrict__ pc,
    void* __restrict__ Cv,
    float* __restrict__ gsum, float* __restrict__ gsq,
    float* __restrict__ aout, float* __restrict__ cout, int* __restrict__ cnt,
    const float* __restrict__ gamma, const float* __restrict__ beta,
    float invN, int M, int nb) {
  __shared__ float s_sum[128];
  __shared__ float s_sq[128];
  __shared__ int s_last;
  const int tid = threadIdx.x;
  const int w = tid >> 6;
  const int lane = tid & 63;
  const int ln = lane & 15;
  const int quad = lane >> 4;
  const int brow = blockIdx.x * 128;
  constexpr int AST = (MODE == 3) ? 16 : KTOT;  // A row stride (fp32 elems)

  int r0 = brow + (w << 5) + ln;       if (r0 >= M) r0 = M - 1;
  int r1 = brow + (w << 5) + 16 + ln;  if (r1 >= M) r1 = M - 1;

  f32x4 acc[2][8];
#pragma unroll
  for (int rt = 0; rt < 2; ++rt)
#pragma unroll
    for (int ct = 0; ct < 8; ++ct) acc[rt][ct] = (f32x4){0.0f, 0.0f, 0.0f, 0.0f};

  constexpr int KC = KTOT / 32;
#pragma unroll
  for (int kcl = 0; kcl < KC; ++kcl) {
    const int kb = (kcl << 5) + (quad << 3);
    float e0[8], e1[8];
    if constexpr (MODE == 3) {
      if (kb < 16) {
        float4 a0 = *(const float4*)(A + (size_t)r0 * AST + kb);
        float4 a1 = *(const float4*)(A + (size_t)r0 * AST + kb + 4);
        e0[0] = a0.x; e0[1] = a0.y; e0[2] = a0.z; e0[3] = a0.w;
        e0[4] = a1.x; e0[5] = a1.y; e0[6] = a1.z; e0[7] = a1.w;
        float4 b0 = *(const float4*)(A + (size_t)r1 * AST + kb);
        float4 b1 = *(const float4*)(A + (size_t)r1 * AST + kb + 4);
        e1[0] = b0.x; e1[1] = b0.y; e1[2] = b0.z; e1[3] = b0.w;
        e1[4] = b1.x; e1[5] = b1.y; e1[6] = b1.z; e1[7] = b1.w;
      } else {
#pragma unroll
        for (int j = 0; j < 8; ++j) { e0[j] = 0.0f; e1[j] = 0.0f; }
      }
    } else {
      float4 a0 = *(const float4*)(A + (size_t)r0 * AST + kb);
      float4 a1 = *(const float4*)(A + (size_t)r0 * AST + kb + 4);
      float4 b0 = *(const float4*)(A + (size_t)r1 * AST + kb);
      float4 b1 = *(const float4*)(A + (size_t)r1 * AST + kb + 4);
      e0[0] = a0.x; e0[1] = a0.y; e0[2] = a0.z; e0[3] = a0.w;
      e0[4] = a1.x; e0[5] = a1.y; e0[6] = a1.z; e0[7] = a1.w;
      e1[0] = b0.x; e1[1] = b0.y; e1[2] = b0.z; e1[3] = b0.w;
      e1[4] = b1.x; e1[5] = b1.y; e1[6] = b1.z; e1[7] = b1.w;
      if constexpr (MODE == 1) {
        float4 p0 = *(const float4*)(pa + kb);
        float4 p1 = *(const float4*)(pa + kb + 4);
        float4 q0 = *(const float4*)(pc + kb);
        float4 q1 = *(const float4*)(pc + kb + 4);
        float pp[8] = {p0.x, p0.y, p0.z, p0.w, p1.x, p1.y, p1.z, p1.w};
        float qq[8] = {q0.x, q0.y, q0.z, q0.w, q1.x, q1.y, q1.z, q1.w};
#pragma unroll
        for (int j = 0; j < 8; ++j) {
          e0[j] = fmaxf(fmaf(pp[j], e0[j], qq[j]), 0.0f);
          e1[j] = fmaxf(fmaf(pp[j], e1[j], qq[j]), 0.0f);
        }
      } else if constexpr (MODE == 2) {
        uint4 ya = *(const uint4*)(A2u + (size_t)r0 * 128 + kb);
        uint4 yb = *(const uint4*)(A2u + (size_t)r1 * 128 + kb);
        float4 p0 = *(const float4*)(pa + kb);
        float4 p1 = *(const float4*)(pa + kb + 4);
        float4 q0 = *(const float4*)(pc + kb);
        float4 q1 = *(const float4*)(pc + kb + 4);
        float y0a[8] = {bfl(ya.x), bfh(ya.x), bfl(ya.y), bfh(ya.y),
                        bfl(ya.z), bfh(ya.z), bfl(ya.w), bfh(ya.w)};
        float y1a[8] = {bfl(yb.x), bfh(yb.x), bfl(yb.y), bfh(yb.y),
                        bfl(yb.z), bfh(yb.z), bfl(yb.w), bfh(yb.w)};
        float pp[8] = {p0.x, p0.y, p0.z, p0.w, p1.x, p1.y, p1.z, p1.w};
        float qq[8] = {q0.x, q0.y, q0.z, q0.w, q1.x, q1.y, q1.z, q1.w};
#pragma unroll
        for (int j = 0; j < 8; ++j) {
          e0[j] = 0.25f * (e0[j] + fmaxf(fmaf(pp[j], y0a[j], qq[j]), 0.0f));
          e1[j] = 0.25f * (e1[j] + fmaxf(fmaf(pp[j], y1a[j], qq[j]), 0.0f));
        }
      }
    }
    short8 a0h, a0l, a1h, a1l;
    split8(e0, a0h, a0l);
    split8(e1, a1h, a1l);
    const ushort_t* bh_base = Bhi + (((size_t)(kcl << 9) + lane) << 3);
    const ushort_t* bl_base = Blo + (((size_t)(kcl << 9) + lane) << 3);
#pragma unroll
    for (int ct = 0; ct < 8; ++ct) {
      short8 bh = *(const short8*)(bh_base + (ct << 9));
      short8 bl = *(const short8*)(bl_base + (ct << 9));
      acc[0][ct] = __builtin_amdgcn_mfma_f32_16x16x32_bf16(a0h, bh, acc[0][ct], 0, 0, 0);
      acc[0][ct] = __builtin_amdgcn_mfma_f32_16x16x32_bf16(a0l, bh, acc[0][ct], 0, 0, 0);
      acc[0][ct] = __builtin_amdgcn_mfma_f32_16x16x32_bf16(a0h, bl, acc[0][ct], 0, 0, 0);
      acc[1][ct] = __builtin_amdgcn_mfma_f32_16x16x32_bf16(a1h, bh, acc[1][ct], 0, 0, 0);
      acc[1][ct] = __builtin_amdgcn_mfma_f32_16x16x32_bf16(a1l, bh, acc[1][ct], 0, 0, 0);
      acc[1][ct] = __builtin_amdgcn_mfma_f32_16x16x32_bf16(a1h, bl, acc[1][ct], 0, 0, 0);
    }
  }

  // ---- epilogue: bias, stats, store ----
  if (tid < 128) { s_sum[tid] = 0.0f; s_sq[tid] = 0.0f; }
  __syncthreads();
#pragma unroll
  for (int ct = 0; ct < 8; ++ct) {
    int col = (ct << 4) + ln;
    float bsc = bias[col];
    float csum = 0.0f, csq = 0.0f;
#pragma unroll
    for (int rt = 0; rt < 2; ++rt) {
#pragma unroll
      for (int i = 0; i < 4; ++i) {
        int row = brow + (w << 5) + (rt << 4) + (quad << 2) + i;
        if (row < M) {
          float y = acc[rt][ct][i] + bsc;
          csum += y; csq += y * y;
          if constexpr (OUT == 0) {
            ((float*)Cv)[(size_t)row * 128 + col] = y;
          } else {
            ((ushort_t*)Cv)[(size_t)row * 128 + col] = f2bf(y);
          }
        }
      }
    }
    atomicAdd(&s_sum[col], csum);
    atomicAdd(&s_sq[col], csq);
  }
  __syncthreads();
  if (tid < 128) {
    atomicAdd(&gsum[tid], s_sum[tid]);   // relaxed device-scope, no flush
    atomicAdd(&gsq[tid], s_sq[tid]);
  }
  __syncthreads();   // drains vmcnt(0) per wave -> stats atomics complete
  if (tid == 0) {
    int v = __hip_atomic_fetch_add(cnt, 1, __ATOMIC_RELAXED, __HIP_MEMORY_SCOPE_AGENT);
    s_last = (v == nb - 1) ? 1 : 0;
  }
  __syncthreads();
  if (s_last && tid < 128) {
    float s = __hip_atomic_load(&gsum[tid], __ATOMIC_RELAXED, __HIP_MEMORY_SCOPE_AGENT);
    float q = __hip_atomic_load(&gsq[tid], __ATOMIC_RELAXED, __HIP_MEMORY_SCOPE_AGENT);
    float mu = s * invN;
    float var = q * invN - mu * mu;
    float sc = gamma[tid] * rsqrtf(var + BN_EPS);
    aout[tid] = sc;
    cout[tid] = beta[tid] - sc * mu;
  }
}

// ============================ regressor head ============================
__global__ __launch_bounds__(256) void finaldot_kernel(
    const float* __restrict__ Y, const float* __restrict__ a, const float* __restrict__ c,
    const float* __restrict__ Wr2, const float* __restrict__ br2,
    float* __restrict__ out, int N) {
  int wv = threadIdx.x >> 6;
  int lane = threadIdx.x & 63;
  int n = blockIdx.x * 4 + wv;
  if (n >= N) return;
  float2 y = *(const float2*)(Y + (size_t)n * HID + lane * 2);
  int c0 = lane * 2;
  float s = fmaxf(fmaf(a[c0], y.x, c[c0]), 0.0f) * Wr2[c0] +
            fmaxf(fmaf(a[c0 + 1], y.y, c[c0 + 1]), 0.0f) * Wr2[c0 + 1];
  for (int off = 32; off > 0; off >>= 1) s += __shfl_down(s, off, 64);
  if (lane == 0) out[n] = 1.0f / (1.0f + expf(-(s + br2[0])));
}

// ============================ launch ============================
extern "C" void kernel_launch(void* const* d_in, const int* in_sizes, int n_in,
                              void* d_out, int out_size, void* d_ws, size_t ws_size,
                              hipStream_t stream) {
  const float* x     = (const float*)d_in[0];
  const int*   ei    = (const int*)d_in[1];
  const float* eps   = (const float*)d_in[2];
  const float* W1_0  = (const float*)d_in[3];
  const float* b1_0  = (const float*)d_in[4];
  const float* W1    = (const float*)d_in[5];
  const float* b1    = (const float*)d_in[6];
  const float* g_in  = (const float*)d_in[7];
  const float* be_in = (const float*)d_in[8];
  const float* W2    = (const float*)d_in[9];
  const float* b2    = (const float*)d_in[10];
  const float* g_out = (const float*)d_in[11];
  const float* be_out= (const float*)d_in[12];
  const float* Wr1   = (const float*)d_in[13];
  const float* br1   = (const float*)d_in[14];
  const float* gr    = (const float*)d_in[15];
  const float* ber   = (const float*)d_in[16];
  const float* Wr2   = (const float*)d_in[17];
  const float* br2   = (const float*)d_in[18];
  float* out = (float*)d_out;

  const int N = in_sizes[0] / IN_F;   // 100000
  const int E = in_sizes[1] / 2;      // 1600000
  const int* srcv = ei;
  const int* dstv = ei + E;

  // workspace carve
  float* X0    = (float*)d_ws;                  // [N][128] fp32 (Z / H1, in-place)
  float* X1    = X0 + (size_t)N * HID;          // [N][128] fp32 (layer0 intermediate)
  float* SKIP  = X1 + (size_t)N * HID;          // [N][128] fp32
  ushort_t* YB = (ushort_t*)(SKIP + (size_t)N * HID);  // [N][128] bf16 inter-layer Y
  int* colb    = (int*)(YB + (size_t)N * HID);
  int* row_ptr = colb + E;
  int* deg     = row_ptr + (N + 4);
  int* cursor  = deg + N;
  int* bsum    = cursor + N;
  int* boff    = bsum + 256;
  float* arena = (float*)(boff + 256);          // 17 slots x 640 floats
  ushort_t* WB = (ushort_t*)(arena + 17 * 640); // hi blob | lo blob

  hipMemsetAsync(deg, 0, sizeof(int) * N, stream);
  hipMemsetAsync(SKIP, 0, sizeof(float) * (size_t)N * HID, stream);
  hipMemsetAsync(arena, 0, sizeof(float) * 17 * 640, stream);

  // CSR build
  hist_kernel<<<(E + 255) / 256, 256, 0, stream>>>(dstv, deg, E);
  int nbs = (N + 1023) / 1024;
  scan1_kernel<<<nbs, 256, 0, stream>>>(deg, bsum, N);
  scan2_kernel<<<1, 256, 0, stream>>>(bsum, boff, nbs, row_ptr, N, E);
  scan3_kernel<<<nbs, 256, 0, stream>>>(deg, boff, row_ptr, cursor, N);
  fill_kernel<<<(E + 255) / 256, 256, 0, stream>>>(srcv, dstv, cursor, colb, E);
  preconv_kernel<<<dim3(64, 17), 256, 0, stream>>>(W1_0, W1, W2, Wr1, WB);

  const int gg = (N + 127) / 128;
  const float invN = 1.0f / (float)N;
#define SLOT(s) (arena + (s) * 640)
#define SSUM(s) SLOT(s)
#define SSQ(s)  (SLOT(s) + 128)
#define SA(s)   (SLOT(s) + 256)
#define SC(s)   (SLOT(s) + 384)
#define SCNT(s) ((int*)(SLOT(s) + 512))
#define WBH(g)  (WB + ((g) == 0 ? 0 : (8192 + (size_t)((g) - 1) * 32768)))
#define WBL(g)  (WBH(g) + BLOBSZ)

  // ---- layer 0 ----  agg16: x -> X0[N,16]; g0a: X0 -> X1 (fp32); g0b: X1 -> YB (bf16)
  agg16_kernel<<<(N + 31) / 32, 256, 0, stream>>>(x, row_ptr, colb, eps, X0, N);
  gemm_mfma<32, 3, 0><<<gg, 256, 0, stream>>>(
      X0, nullptr, WBH(0), WBL(0), b1_0, nullptr, nullptr, X1,
      SSUM(0), SSQ(0), SA(0), SC(0), SCNT(0), g_in, be_in, invN, N, gg);
  gemm_mfma<128, 1, 1><<<gg, 256, 0, stream>>>(
      X1, nullptr, WBH(8), WBL(8), b2, SA(0), SC(0), YB,
      SSUM(1), SSQ(1), SA(1), SC(1), SCNT(1), g_out, be_out, invN, N, gg);
  // Y0 in YB (bf16)

  // ---- layers 1..7 ----  agg: YB->X0 (fp32 Z); gemm1: X0->X0 in place; gemm2: X0->YB
  for (int L = 1; L < NLAYERS; ++L) {
    int sp = 2 * L - 1;
    int s0 = 2 * L, s1 = 2 * L + 1;
    float* skipw = ((L - 1) & 1) ? SKIP : nullptr;  // fold h_{L-1} at L=2,4,6
    agg128_kernel<<<(N + 3) / 4, 256, 0, stream>>>(
        YB, SA(sp), SC(sp), row_ptr, colb, eps, L, X0, skipw, N);
    gemm_mfma<128, 0, 0><<<gg, 256, 0, stream>>>(
        X0, nullptr, WBH(L), WBL(L), b1 + (size_t)(L - 1) * HID, nullptr, nullptr, X0,
        SSUM(s0), SSQ(s0), SA(s0), SC(s0), SCNT(s0),
        g_in + (size_t)L * HID, be_in + (size_t)L * HID, invN, N, gg);
    gemm_mfma<128, 1, 1><<<gg, 256, 0, stream>>>(
        X0, nullptr, WBH(8 + L), WBL(8 + L), b2 + (size_t)L * HID, SA(s0), SC(s0), YB,
        SSUM(s1), SSQ(s1), SA(s1), SC(s1), SCNT(s1),
        g_out + (size_t)L * HID, be_out + (size_t)L * HID, invN, N, gg);
  }
  // Y7 in YB (bf16), slot 15 holds its outer-BN params

  // ---- regressor: op = 0.25*(SKIP + relu(a7*Y7+c7)), Y7 bf16 ----
  gemm_mfma<128, 2, 0><<<gg, 256, 0, stream>>>(
      SKIP, YB, WBH(16), WBL(16), br1, SA(15), SC(15), X0,
      SSUM(16), SSQ(16), SA(16), SC(16), SCNT(16), gr, ber, invN, N, gg);
  finaldot_kernel<<<(N + 3) / 4, 256, 0, stream>>>(X0, SA(16), SC(16), Wr2, br2, out, N);
#undef SLOT
#undef SSUM
#undef SSQ
#undef SA
#undef SC
#undef SCNT
#undef WBH
#undef WBL
}